// Round 1
// 441.846 us; speedup vs baseline: 1.0659x; 1.0659x over previous
//
#include <hip/hip_runtime.h>

// Fused 16-expert, 2-layer Linear+ReLU stack, v2.
//   x  [524288, 128] fp32 -> 16 slices of 32768 tokens
//   W  [16, 2, 128, 128] fp32 (torch [out,in]) ; b [16, 2, 128] fp32
//
// v2 strategy:
//  - prologue kernel converts W once to bf16 in MFMA *fragment-major* layout
//    (g_Wf): chunk fid=gt*4+kt of model/layer is 64 lanes x 16B, lane-ordered.
//  - main kernel stages W0+W1 via global_load_lds (16B, async, no VALU, no
//    ds_writes, conflict-free) BOTH at kernel start; x prefetched to regs
//    under the same latency. 3 barriers total, no mid-kernel staging stall.
//  - MFMA operands swapped: D = W_frag x x_frag -> D col=token, row=feature.
//    Thread owns 4 consecutive features of one token => sY writes are
//    ds_write_b64 and output stores are coalesced float4.
//  - BM=128 tokens/block, 512 thr (8 waves); LDS 68.6KB -> 2 blocks/CU
//    = 16 waves/CU.

#define NF   128
#define NM   16
#define NTOK 524288
#define TPM  (NTOK / NM)     // 32768 tokens per model
#define BM   128             // tokens per block
#define BPM  (TPM / BM)      // 256 blocks per model
#define WPAD 136             // sY row pitch in bf16 elems (272B, 16B-aligned)

typedef __attribute__((ext_vector_type(8))) short bf16x8;
typedef __attribute__((ext_vector_type(4))) short bf16x4v;
typedef __attribute__((ext_vector_type(4))) float f32x4;
typedef unsigned int u32;

__device__ __forceinline__ unsigned short f2bf(float f) {
    union { float f; unsigned u; } v; v.f = f;
    unsigned r = v.u + 0x7FFFu + ((v.u >> 16) & 1u);   // RNE
    return (unsigned short)(r >> 16);
}

// bf16 W in fragment-major layout: [m][l][fid=gt*4+kt][lane][8 elems]
__device__ alignas(16) unsigned short g_Wf[NM * 2 * NF * NF];   // 1 MiB

__global__ __launch_bounds__(256) void convw_kernel(const float* __restrict__ W) {
    const int idx  = blockIdx.x * 256 + threadIdx.x;  // 65536 fragment-lanes
    const int lane = idx & 63;
    const int fid  = (idx >> 6) & 31;
    const int ml   = idx >> 11;                       // m*2 + l
    const int row  = (fid >> 2) * 16 + (lane & 15);   // out-feature
    const int col  = (fid & 3) * 32 + (lane >> 4) * 8;// in-feature (k)
    const float* s = W + ((size_t)ml * NF + row) * NF + col;
    float4 a = *(const float4*)s;
    float4 c = *(const float4*)(s + 4);
    unsigned short* d = &g_Wf[(size_t)idx * 8];
    d[0] = f2bf(a.x); d[1] = f2bf(a.y); d[2] = f2bf(a.z); d[3] = f2bf(a.w);
    d[4] = f2bf(c.x); d[5] = f2bf(c.y); d[6] = f2bf(c.z); d[7] = f2bf(c.w);
}

__device__ __forceinline__ void load_lds16(const unsigned short* g, unsigned short* l) {
    __builtin_amdgcn_global_load_lds(
        (const __attribute__((address_space(1))) u32*)g,
        (__attribute__((address_space(3))) u32*)l, 16, 0, 0);
}

__global__ __launch_bounds__(512, 4) void mlp16_kernel(
        const float* __restrict__ x, const float* __restrict__ b,
        float* __restrict__ out) {
    // buf0: W0 fragments (32768B), later overlaid by sY [BM][WPAD] (34816B)
    __shared__ alignas(16) unsigned short buf0[BM * WPAD];
    __shared__ alignas(16) unsigned short sW1[NF * NF];
    __shared__ alignas(16) float sB[2 * NF];

    const int t    = threadIdx.x;
    const int w    = t >> 6;       // wave 0..7, owns tokens w*16..w*16+15
    const int lane = t & 63;
    const int ln   = lane & 15;    // token within wave's 16-group
    const int q    = lane >> 4;    // k-octet / feature-quad select

    const int m    = blockIdx.x >> 8;          // BPM = 256
    const int tile = blockIdx.x & (BPM - 1);
    const int row0 = m * TPM + tile * BM;

    if (t < 2 * NF) sB[t] = b[m * 2 * NF + t];

    // ---- async-stage W0 + W1 fragments (wave w: fids w*4..w*4+3) ----
    const unsigned short* wsrc = g_Wf + (size_t)m * 2 * NF * NF;
    #pragma unroll
    for (int i = 0; i < 4; ++i) {
        const int fid = w * 4 + i;
        load_lds16(wsrc + (size_t)(fid * 64 + lane) * 8, &buf0[fid * 512]);
        load_lds16(wsrc + NF * NF + (size_t)(fid * 64 + lane) * 8, &sW1[fid * 512]);
    }

    // ---- prefetch this thread's x slice into regs (hides staging latency) ----
    const float* xrow = x + (size_t)(row0 + w * 16 + ln) * NF;
    float4 xa[8];
    #pragma unroll
    for (int kt = 0; kt < 4; ++kt) {
        xa[2 * kt]     = *(const float4*)(xrow + kt * 32 + q * 8);
        xa[2 * kt + 1] = *(const float4*)(xrow + kt * 32 + q * 8 + 4);
    }

    __syncthreads();   // staging + sB complete (barrier drains vmcnt)

    // ---- layer 1: A = W0 fragment, B = x fragment ----
    // D row = out-feature gt*16+q*4+r, D col = token ln
    f32x4 acc[8];
    #pragma unroll
    for (int gt = 0; gt < 8; ++gt) acc[gt] = (f32x4){0.f, 0.f, 0.f, 0.f};

    #pragma unroll
    for (int kt = 0; kt < 4; ++kt) {
        const float4 a0 = xa[2 * kt], a1 = xa[2 * kt + 1];
        bf16x8 xb;
        xb[0] = (short)f2bf(a0.x); xb[1] = (short)f2bf(a0.y);
        xb[2] = (short)f2bf(a0.z); xb[3] = (short)f2bf(a0.w);
        xb[4] = (short)f2bf(a1.x); xb[5] = (short)f2bf(a1.y);
        xb[6] = (short)f2bf(a1.z); xb[7] = (short)f2bf(a1.w);
        #pragma unroll
        for (int gt = 0; gt < 8; ++gt) {
            bf16x8 wf = *(const bf16x8*)&buf0[((gt * 4 + kt) * 64 + lane) * 8];
            acc[gt] = __builtin_amdgcn_mfma_f32_16x16x32_bf16(wf, xb, acc[gt], 0, 0, 0);
        }
    }

    __syncthreads();   // all waves done reading W0 before sY overlays it

    // ---- bias + relu -> sY (bf16): row = token, col = feature ----
    #pragma unroll
    for (int gt = 0; gt < 8; ++gt) {
        const f32x4 bv = *(const f32x4*)&sB[gt * 16 + q * 4];
        bf16x4v yv;
        #pragma unroll
        for (int r = 0; r < 4; ++r) {
            float v = acc[gt][r] + bv[r];
            v = v > 0.f ? v : 0.f;
            yv[r] = (short)f2bf(v);
        }
        *(bf16x4v*)&buf0[(w * 16 + ln) * WPAD + gt * 16 + q * 4] = yv;
    }

    __syncthreads();

    // ---- layer 2: A = W1 fragment, B = sY fragment ----
    f32x4 acc2[8];
    #pragma unroll
    for (int gt = 0; gt < 8; ++gt) acc2[gt] = (f32x4){0.f, 0.f, 0.f, 0.f};

    const unsigned short* yrow = &buf0[(w * 16 + ln) * WPAD];
    #pragma unroll
    for (int kt = 0; kt < 4; ++kt) {
        const bf16x8 yb = *(const bf16x8*)(yrow + kt * 32 + q * 8);
        #pragma unroll
        for (int gt = 0; gt < 8; ++gt) {
            bf16x8 wf = *(const bf16x8*)&sW1[((gt * 4 + kt) * 64 + lane) * 8];
            acc2[gt] = __builtin_amdgcn_mfma_f32_16x16x32_bf16(wf, yb, acc2[gt], 0, 0, 0);
        }
    }

    // ---- bias + relu -> out: coalesced float4 per gt ----
    float* orow = out + (size_t)(row0 + w * 16 + ln) * NF;
    #pragma unroll
    for (int gt = 0; gt < 8; ++gt) {
        const f32x4 bv = *(const f32x4*)&sB[NF + gt * 16 + q * 4];
        float4 o;
        float v0 = acc2[gt][0] + bv[0]; o.x = v0 > 0.f ? v0 : 0.f;
        float v1 = acc2[gt][1] + bv[1]; o.y = v1 > 0.f ? v1 : 0.f;
        float v2 = acc2[gt][2] + bv[2]; o.z = v2 > 0.f ? v2 : 0.f;
        float v3 = acc2[gt][3] + bv[3]; o.w = v3 > 0.f ? v3 : 0.f;
        *(float4*)(orow + gt * 16 + q * 4) = o;
    }
}

extern "C" void kernel_launch(void* const* d_in, const int* in_sizes, int n_in,
                              void* d_out, int out_size, void* d_ws, size_t ws_size,
                              hipStream_t stream) {
    const float* x = (const float*)d_in[0];
    const float* W = (const float*)d_in[1];
    const float* b = (const float*)d_in[2];
    float* out = (float*)d_out;
    convw_kernel<<<dim3(256), dim3(256), 0, stream>>>(W);
    mlp16_kernel<<<dim3(NTOK / BM), dim3(512), 0, stream>>>(x, b, out);
}